// Round 8
// baseline (377.760 us; speedup 1.0000x reference)
//
#include <hip/hip_runtime.h>
#include <math.h>

#define NE 8
#define NH 2048
#define NI 1024
#define NT 512
#define NTOPK 2
#define NR 16
#define NGROUP 64
#define NPAIR (NT*NTOPK)   // 1024

typedef short bf16x8 __attribute__((ext_vector_type(8)));
typedef float f32x16 __attribute__((ext_vector_type(16)));
typedef unsigned int u32;

#define MFMA32 __builtin_amdgcn_mfma_f32_32x32x16_bf16

__device__ const float NF4_TAB[16] = {
    -1.0f, -0.6961928009986877f, -0.5250730514526367f, -0.39491748809814453f,
    -0.28444138169288635f, -0.18477343022823334f, -0.09105003625154495f, 0.0f,
    0.07958029955625534f, 0.16093020141124725f, 0.24611230194568634f,
    0.33791524171829224f, 0.44070982933044434f, 0.5626170039176941f,
    0.7229568362236328f, 1.0f};

// ---------------- workspace layout (bytes) ----------------
#define OFF_EXPOFF 0         // int[16]
#define OFF_TOK    256       // int[1024]
#define OFF_EXP    4352      // int[1024]
#define OFF_W      8448      // float[1024]
#define OFF_XAG    12544     // ushort[1024*16] bf16
#define OFF_XAU    45312     // ushort[1024*16]
#define OFF_HA     78080     // ushort[1024*16]
#define OFF_XC     131072    // ushort[1024*2048] compacted bf16 x rows (4 MB)
#define OFF_GU     4325376   // ushort[2*1024*1024] gate|up results (4 MB)
#define OFF_HBUF   8519680   // ushort[1024*1024] bf16 h (2 MB)

__device__ inline u32 f2bf(float f) {
    return (__float_as_uint(f) + 0x8000u) >> 16;
}
__device__ inline u32 bfpack2(float a, float b) {
    return ((__float_as_uint(a) + 0x8000u) >> 16) |
           ((__float_as_uint(b) + 0x8000u) & 0xFFFF0000u);
}
__device__ inline bf16x8 asbf(uint4 w) {
    union { uint4 u; bf16x8 b; } c; c.u = w; return c.b;
}
__device__ inline bf16x8 bfzero() { return asbf(make_uint4(0,0,0,0)); }
__device__ inline float bf2f(u32 v) { return __uint_as_float(v << 16); }

// async global->LDS; LDS dest = wave-uniform base + lane*16
__device__ __forceinline__ void stage16(const void* g, void* l) {
    __builtin_amdgcn_global_load_lds(
        (const __attribute__((address_space(1))) u32*)g,
        (__attribute__((address_space(3))) u32*)l, 16, 0, 0);
}

// single-wave pipeline waits (1-wave blocks, no __syncthreads in K-loop)
#define WAIT_PREV_STAGE() asm volatile("s_waitcnt vmcnt(8)" ::: "memory")
#define WAIT_ALL()        asm volatile("s_waitcnt vmcnt(0)" ::: "memory")

// -------- kernel 1: routing compaction --------
__global__ __launch_bounds__(1024) void k_route(const int* __restrict__ idx,
                                                const float* __restrict__ w,
                                                int* expert_off, int* ptok,
                                                int* pexp, float* pw) {
    __shared__ int cnt[NE], off[NE + 1], cur[NE];
    int tid = threadIdx.x;
    if (tid < NE) cnt[tid] = 0;
    __syncthreads();
    int e = idx[tid];
    float wt = w[tid];
    int t = tid >> 1;
    atomicAdd(&cnt[e], 1);
    __syncthreads();
    if (tid == 0) {
        off[0] = 0;
        for (int i = 0; i < NE; i++) off[i + 1] = off[i] + cnt[i];
    }
    __syncthreads();
    if (tid < NE) cur[tid] = off[tid];
    __syncthreads();
    int pos = atomicAdd(&cur[e], 1);
    ptok[pos] = t; pexp[pos] = e; pw[pos] = wt;
    if (tid <= NE) expert_off[tid] = off[tid];
}

// -------- kernel 2: gather+convert x rows into compact xc[pair][k] bf16 -----
__global__ __launch_bounds__(256) void k_prep(const float* __restrict__ x,
                                              const int* __restrict__ ptok,
                                              unsigned short* __restrict__ xc) {
    int p = blockIdx.x;
    int t = ptok[p];
    const float* src = x + (size_t)t * NH;
    unsigned short* dst = xc + (size_t)p * NH;
    int i = threadIdx.x * 8;
    float4 v0 = *(const float4*)(src + i);
    float4 v1 = *(const float4*)(src + i + 4);
    uint4 w;
    w.x = bfpack2(v0.x, v0.y); w.y = bfpack2(v0.z, v0.w);
    w.z = bfpack2(v1.x, v1.y); w.w = bfpack2(v1.z, v1.w);
    *(uint4*)(dst + i) = w;
}

// -------- kernel 3: xA[p][r] = x . A (per-expert tiles, A read once/block) ---
__global__ __launch_bounds__(256) void k_xA(const unsigned short* __restrict__ xc,
                                            const float* __restrict__ gA,
                                            const float* __restrict__ uA,
                                            const int* __restrict__ expert_off,
                                            unsigned short* __restrict__ xAg,
                                            unsigned short* __restrict__ xAu) {
    int e = blockIdx.x;
    int off = expert_off[e], cnt = expert_off[e + 1] - off;
    int p0 = blockIdx.y * 16;
    if (p0 >= cnt) return;
    int tid = threadIdx.x;
    int r = tid & 15, p = tid >> 4;
    int pcl = p0 + p; if (pcl > cnt - 1) pcl = cnt - 1;
    const unsigned short* xrow = xc + (size_t)(off + pcl) * NH;
    const float* gAe = gA + (size_t)e * NH * NR + r;
    const float* uAe = uA + (size_t)e * NH * NR + r;
    float sg = 0.f, su = 0.f;
    for (int k = 0; k < NH; k += 2) {
        u32 xx = *(const u32*)(xrow + k);
        float x0 = bf2f(xx & 0xFFFFu), x1 = bf2f(xx >> 16);
        sg += x0 * gAe[(size_t)k * NR] + x1 * gAe[(size_t)(k + 1) * NR];
        su += x0 * uAe[(size_t)k * NR] + x1 * uAe[(size_t)(k + 1) * NR];
    }
    if (p0 + p < cnt) {
        xAg[(size_t)(off + p0 + p) * NR + r] = (unsigned short)f2bf(sg);
        xAu[(size_t)(off + p0 + p) * NR + r] = (unsigned short)f2bf(su);
    }
}

// -------- kernel 4: gate OR up grouped GEMM --------
// 1 wave/block, tile 32 rows x 32 cols, 3-buffer vmcnt(8) pipeline.
// A-rows compact in xc: staged as 8 rows x 128B per instr, XOR-swizzled chunks.
__global__ __launch_bounds__(64) void k_gu(
    const unsigned short* __restrict__ xc,
    const int* __restrict__ gpk, const float* __restrict__ gsc,
    const int* __restrict__ upk, const float* __restrict__ usc,
    const float* __restrict__ gB, const float* __restrict__ uB,
    const unsigned short* __restrict__ xAg, const unsigned short* __restrict__ xAu,
    const int* __restrict__ expert_off,
    unsigned short* __restrict__ gu)
{
    __shared__ u32 lut[256];                  // bf16-pair dequant LUT, 1 KB
    __shared__ u32 code[3][1024];             // [prow32][col32], 3x4 KB
    __shared__ unsigned short ax[3][2048];    // [row32][chunk8][8], 3x4 KB
    __shared__ float sclb[32][32];            // [step][col], 4 KB

    int lane = threadIdx.x;
    int q = lane >> 5, cw = lane & 31;
    for (int i = lane; i < 256; i += 64)
        lut[i] = bfpack2(NF4_TAB[i & 15], NF4_TAB[(i >> 4) & 15]);

    int e = blockIdx.x;
    int c0 = blockIdx.y * 32;
    int mat = blockIdx.z & 1;
    int rt = blockIdx.z >> 1;                 // row-tile 0..3
    const u32* pk = (const u32*)(mat ? upk : gpk);
    const float* scp = mat ? usc : gsc;
    const float* Bp = mat ? uB : gB;
    const unsigned short* xA = mat ? xAu : xAg;

    int off = expert_off[e];
    int cnt = expert_off[e + 1] - off;
    int colg = c0 + cw;
    const size_t pkb = (size_t)e * (NH / 2) * NI;

    {   // stage all 32 per-step scales once per block
        const float* sg = scp + (size_t)e * (NH / NGROUP) * NI + c0;
        #pragma unroll
        for (int g = 0; g < 4; ++g)
            stage16(sg + (size_t)(g * 8 + (lane >> 3)) * NI + ((lane & 7) << 2),
                    &sclb[g * 8][0]);
    }

    // per-lane invariants
    int tr8 = lane >> 3;                      // row within 8-row group
    int cs = (lane & 7) ^ tr8;                // swizzled source chunk
    const size_t wbase = pkb + (size_t)tr8 * NI + c0 + ((lane & 7) << 2);

    const int NS = NH / 64;                   // 32 K-steps
    for (int s0 = rt * 32; s0 < cnt; s0 += 128) {
        u32 xbase[4];
        #pragma unroll
        for (int g = 0; g < 4; ++g) {
            int rr = s0 + (g << 3) + tr8; if (rr > cnt - 1) rr = cnt - 1;
            xbase[g] = (u32)(off + rr) * (u32)NH + (u32)(cs << 3);
        }

        auto stage = [&](int b, int k0) {     // exactly 8 global_load_lds
            int kp0 = k0 >> 1;
            #pragma unroll
            for (int g = 0; g < 4; ++g)
                stage16(pk + wbase + (size_t)(kp0 + (g << 3)) * NI,
                        &code[b][g << 8]);
            #pragma unroll
            for (int g = 0; g < 4; ++g)
                stage16(xc + xbase[g] + k0, &ax[b][g << 9]);
        };

        f32x16 acc;
        #pragma unroll
        for (int i = 0; i < 16; ++i) acc[i] = 0.f;

        stage(0, 0);
        stage(1, 64);
        for (int s = 0; s < NS; ++s) {
            if (s + 1 < NS) WAIT_PREV_STAGE(); else WAIT_ALL();
            if (s + 2 < NS) stage((s + 2) % 3, (s + 2) * 64);
            int b = s % 3;
            float scl = sclb[s][cw];
            f32x16 t;
            #pragma unroll
            for (int i = 0; i < 16; ++i) t[i] = 0.f;
            #pragma unroll
            for (int ks = 0; ks < 4; ++ks) {
                int ch_ = ((ks << 1) | q) ^ (cw & 7);
                bf16x8 a = *(const bf16x8*)&ax[b][(cw << 6) + (ch_ << 3)];
                uint4 w4; u32* wp = &w4.x;
                #pragma unroll
                for (int i = 0; i < 4; ++i)
                    wp[i] = lut[code[b][(((ks << 3) + (q << 2) + i) << 5) + cw] & 255];
                t = MFMA32(a, asbf(w4), t, 0, 0, 0);
            }
            #pragma unroll
            for (int i = 0; i < 16; ++i) acc[i] += scl * t[i];
        }

        // LoRA extension: += (x.A) . B  (K = 16)
        {
            bf16x8 la = bfzero();
            if (s0 + cw < cnt)
                la = *(const bf16x8*)(xA + (size_t)(off + s0 + cw) * NR + (q << 3));
            const float* Bq = Bp + ((size_t)e * NR + (q << 3)) * NI + colg;
            uint4 w4; u32* wp = &w4.x;
            #pragma unroll
            for (int i = 0; i < 4; ++i)
                wp[i] = bfpack2(Bq[(2 * i) * NI], Bq[(2 * i + 1) * NI]);
            acc = MFMA32(la, asbf(w4), acc, 0, 0, 0);
        }
        // epilogue: store bf16 tile. C row = (reg&3) + 8*(reg>>2) + 4*q
        unsigned short* outb = gu + (size_t)mat * NPAIR * NI;
        #pragma unroll
        for (int reg = 0; reg < 16; ++reg) {
            int rloc = (reg & 3) + 8 * (reg >> 2) + (q << 2);
            if (s0 + rloc < cnt)
                outb[(size_t)(off + s0 + rloc) * NI + colg] =
                    (unsigned short)f2bf(acc[reg]);
        }
    }
}

// -------- kernel 5: h = silu(gate)*up --------
__global__ __launch_bounds__(256) void k_swiglu(const unsigned short* __restrict__ gu,
                                                unsigned short* __restrict__ hbuf) {
    int i = (blockIdx.x * 256 + threadIdx.x) * 8;
    uint4 gv = *(const uint4*)(gu + i);
    uint4 uv = *(const uint4*)(gu + (size_t)NPAIR * NI + i);
    const u32* gp = &gv.x; const u32* up = &uv.x;
    uint4 hv; u32* hp = &hv.x;
    #pragma unroll
    for (int j = 0; j < 4; ++j) {
        float g0 = bf2f(gp[j] & 0xFFFFu), g1 = bf2f(gp[j] >> 16);
        float u0 = bf2f(up[j] & 0xFFFFu), u1 = bf2f(up[j] >> 16);
        float h0 = g0 * u0 / (1.f + __expf(-g0));
        float h1 = g1 * u1 / (1.f + __expf(-g1));
        hp[j] = bfpack2(h0, h1);
    }
    *(uint4*)(hbuf + i) = hv;
}

// -------- kernel 6: hA[p][r] = h . down_A (per-expert tiles) --------
__global__ __launch_bounds__(256) void k_hA(const unsigned short* __restrict__ hbuf,
                                            const float* __restrict__ dA,
                                            const int* __restrict__ expert_off,
                                            unsigned short* __restrict__ hA) {
    int e = blockIdx.x;
    int off = expert_off[e], cnt = expert_off[e + 1] - off;
    int p0 = blockIdx.y * 16;
    if (p0 >= cnt) return;
    int tid = threadIdx.x;
    int r = tid & 15, p = tid >> 4;
    int pcl = p0 + p; if (pcl > cnt - 1) pcl = cnt - 1;
    const unsigned short* hrow = hbuf + (size_t)(off + pcl) * NI;
    const float* dAe = dA + (size_t)e * NI * NR + r;
    float s = 0.f;
    for (int k = 0; k < NI; k += 2) {
        u32 xx = *(const u32*)(hrow + k);
        s += bf2f(xx & 0xFFFFu) * dAe[(size_t)k * NR]
           + bf2f(xx >> 16) * dAe[(size_t)(k + 1) * NR];
    }
    if (p0 + p < cnt)
        hA[(size_t)(off + p0 + p) * NR + r] = (unsigned short)f2bf(s);
}

// -------- kernel 7: down GEMM (same pipeline, compact h rows) + combine ------
__global__ __launch_bounds__(64) void k_dn(
    const unsigned short* __restrict__ hbuf,
    const int* __restrict__ dpk, const float* __restrict__ dsc,
    const float* __restrict__ dB,
    const unsigned short* __restrict__ hA,
    const int* __restrict__ expert_off, const int* __restrict__ ptok,
    const float* __restrict__ pw,
    float* __restrict__ out)
{
    __shared__ u32 lut[256];
    __shared__ u32 code[3][1024];
    __shared__ unsigned short ax[3][2048];
    __shared__ float sclb[16][32];

    int lane = threadIdx.x;
    int q = lane >> 5, cw = lane & 31;
    for (int i = lane; i < 256; i += 64)
        lut[i] = bfpack2(NF4_TAB[i & 15], NF4_TAB[(i >> 4) & 15]);

    int e = blockIdx.x;
    int c0 = blockIdx.y * 32;
    int rt = blockIdx.z;                      // 0..3
    const u32* pk = (const u32*)dpk;

    int off = expert_off[e];
    int cnt = expert_off[e + 1] - off;
    int colg = c0 + cw;
    const size_t pkb = (size_t)e * (NI / 2) * NH;

    {
        const float* sg = dsc + (size_t)e * (NI / NGROUP) * NH + c0;
        #pragma unroll
        for (int g = 0; g < 2; ++g)
            stage16(sg + (size_t)(g * 8 + (lane >> 3)) * NH + ((lane & 7) << 2),
                    &sclb[g * 8][0]);
    }

    int tr8 = lane >> 3;
    int cs = (lane & 7) ^ tr8;
    const size_t wbase = pkb + (size_t)tr8 * NH + c0 + ((lane & 7) << 2);

    const int NS = NI / 64;                   // 16 K-steps
    for (int s0 = rt * 32; s0 < cnt; s0 += 128) {
        u32 xbase[4];
        #pragma unroll
        for (int g = 0; g < 4; ++g) {
            int rr = s0 + (g << 3) + tr8; if (rr > cnt - 1) rr = cnt - 1;
            xbase[g] = (u32)(off + rr) * (u32)NI + (u32)(cs << 3);
        }

        auto stage = [&](int b, int k0) {
            int kp0 = k0 >> 1;
            #pragma unroll
            for (int g = 0; g < 4; ++g)
                stage16(pk + wbase + (size_t)(kp0 + (g << 3)) * NH,
                        &code[b][g << 8]);
            #pragma unroll
            for (int g = 0; g < 4; ++g)
                stage16(hbuf + xbase[g] + k0, &ax[b][g << 9]);
        };

        f32x16 acc;
        #pragma unroll
        for (int i = 0; i < 16; ++i) acc[i] = 0.f;

        stage(0, 0);
        stage(1, 64);
        for (int s = 0; s < NS; ++s) {
            if (s + 1 < NS) WAIT_PREV_STAGE(); else WAIT_ALL();
            if (s + 2 < NS) stage((s + 2) % 3, (s + 2) * 64);
            int b = s % 3;
            float scl = sclb[s][cw];
            f32x16 t;
            #pragma unroll
            for (int i = 0; i < 16; ++i) t[i] = 0.f;
            #pragma unroll
            for (int ks = 0; ks < 4; ++ks) {
                int ch_ = ((ks << 1) | q) ^ (cw & 7);
                bf16x8 a = *(const bf16x8*)&ax[b][(cw << 6) + (ch_ << 3)];
                uint4 w4; u32* wp = &w4.x;
                #pragma unroll
                for (int i = 0; i < 4; ++i)
                    wp[i] = lut[code[b][(((ks << 3) + (q << 2) + i) << 5) + cw] & 255];
                t = MFMA32(a, asbf(w4), t, 0, 0, 0);
            }
            #pragma unroll
            for (int i = 0; i < 16; ++i) acc[i] += scl * t[i];
        }

        // LoRA extension: += (h.down_A) . down_B (K = 16)
        {
            bf16x8 la = bfzero();
            if (s0 + cw < cnt)
                la = *(const bf16x8*)(hA + (size_t)(off + s0 + cw) * NR + (q << 3));
            const float* Bq = dB + ((size_t)e * NR + (q << 3)) * NH + colg;
            uint4 w4; u32* wp = &w4.x;
            #pragma unroll
            for (int i = 0; i < 4; ++i)
                wp[i] = bfpack2(Bq[(2 * i) * NH], Bq[(2 * i + 1) * NH]);
            acc = MFMA32(la, asbf(w4), acc, 0, 0, 0);
        }
        // epilogue: weighted atomic combine
        #pragma unroll
        for (int reg = 0; reg < 16; ++reg) {
            int rloc = (reg & 3) + 8 * (reg >> 2) + (q << 2);
            if (s0 + rloc < cnt) {
                int p = off + s0 + rloc;
                atomicAdd(&out[(size_t)ptok[p] * NH + colg], acc[reg] * pw[p]);
            }
        }
    }
}

extern "C" void kernel_launch(void* const* d_in, const int* in_sizes, int n_in,
                              void* d_out, int out_size, void* d_ws,
                              size_t ws_size, hipStream_t stream) {
    const float* x = (const float*)d_in[0];
    const int* topk_idx = (const int*)d_in[1];
    const float* topk_w = (const float*)d_in[2];
    const int* gate_packed = (const int*)d_in[3];
    const float* gate_scales = (const float*)d_in[4];
    const int* up_packed = (const int*)d_in[5];
    const float* up_scales = (const float*)d_in[6];
    const int* down_packed = (const int*)d_in[7];
    const float* down_scales = (const float*)d_in[8];
    const float* gate_A = (const float*)d_in[9];
    const float* gate_B = (const float*)d_in[10];
    const float* up_A = (const float*)d_in[11];
    const float* up_B = (const float*)d_in[12];
    const float* down_A = (const float*)d_in[13];
    const float* down_B = (const float*)d_in[14];
    float* out = (float*)d_out;

    char* ws = (char*)d_ws;
    int* expert_off = (int*)(ws + OFF_EXPOFF);
    int* ptok = (int*)(ws + OFF_TOK);
    int* pexp = (int*)(ws + OFF_EXP);
    float* pw = (float*)(ws + OFF_W);
    unsigned short* xAg = (unsigned short*)(ws + OFF_XAG);
    unsigned short* xAu = (unsigned short*)(ws + OFF_XAU);
    unsigned short* hA = (unsigned short*)(ws + OFF_HA);
    unsigned short* xc = (unsigned short*)(ws + OFF_XC);
    unsigned short* gu = (unsigned short*)(ws + OFF_GU);
    unsigned short* hbuf = (unsigned short*)(ws + OFF_HBUF);

    hipMemsetAsync(d_out, 0, (size_t)NT * NH * sizeof(float), stream);

    k_route<<<1, 1024, 0, stream>>>(topk_idx, topk_w, expert_off, ptok, pexp, pw);
    k_prep<<<NPAIR, 256, 0, stream>>>(x, ptok, xc);
    k_xA<<<dim3(NE, 16), 256, 0, stream>>>(xc, gate_A, up_A, expert_off, xAg, xAu);
    k_gu<<<dim3(NE, NI / 32, 8), 64, 0, stream>>>(
        xc, gate_packed, gate_scales, up_packed, up_scales, gate_B, up_B,
        xAg, xAu, expert_off, gu);
    k_swiglu<<<(NPAIR * NI) / (256 * 8), 256, 0, stream>>>(gu, hbuf);
    k_hA<<<dim3(NE, 16), 256, 0, stream>>>(hbuf, down_A, expert_off, hA);
    k_dn<<<dim3(NE, NH / 32, 4), 64, 0, stream>>>(
        hbuf, down_packed, down_scales, down_B, hA, expert_off, ptok, pw, out);
}